// Round 3
// baseline (792.562 us; speedup 1.0000x reference)
//
#include <hip/hip_runtime.h>
#include <math.h>

#define BB 2
#define TT 2048
#define DD 1024
#define HH 16
#define DH 64
#define BTOT (BB*TT)
#define NEG_INF (-1e30f)

// ---------------- router: logits -> softmax probs -> top-4 gate ----------------
__global__ __launch_bounds__(64) void router_kernel(const float* __restrict__ x,
                                                    const float* __restrict__ Wr,
                                                    float* __restrict__ gates) {
  const int row = blockIdx.x;
  const int lane = threadIdx.x;
  const float* xr = x + (size_t)row * DD;
  float acc[16];
#pragma unroll
  for (int c = 0; c < 16; ++c) acc[c] = 0.f;
  for (int d = lane; d < DD; d += 64) {
    float xv = xr[d];
    const float4* wrow = reinterpret_cast<const float4*>(Wr + (size_t)d * HH);
#pragma unroll
    for (int g = 0; g < 4; ++g) {
      float4 w = wrow[g];
      acc[g*4+0] = fmaf(xv, w.x, acc[g*4+0]);
      acc[g*4+1] = fmaf(xv, w.y, acc[g*4+1]);
      acc[g*4+2] = fmaf(xv, w.z, acc[g*4+2]);
      acc[g*4+3] = fmaf(xv, w.w, acc[g*4+3]);
    }
  }
#pragma unroll
  for (int c = 0; c < 16; ++c) {
    float v = acc[c];
    v += __shfl_down(v, 32);
    v += __shfl_down(v, 16);
    v += __shfl_down(v, 8);
    v += __shfl_down(v, 4);
    v += __shfl_down(v, 2);
    v += __shfl_down(v, 1);
    acc[c] = v;
  }
  if (lane == 0) {
    float mx = acc[0];
#pragma unroll
    for (int c = 1; c < 16; ++c) mx = fmaxf(mx, acc[c]);
    float e[16]; float den = 0.f;
#pragma unroll
    for (int c = 0; c < 16; ++c) { e[c] = __expf(acc[c] - mx); den += e[c]; }
    // 4th-largest logit (softmax is monotone, so logit-domain threshold == prob-domain)
    float tmp[16];
#pragma unroll
    for (int c = 0; c < 16; ++c) tmp[c] = acc[c];
    float th = NEG_INF;
    for (int it = 0; it < 4; ++it) {
      float bv = NEG_INF; int bi = 0;
      for (int c = 0; c < 16; ++c) { if (tmp[c] > bv) { bv = tmp[c]; bi = c; } }
      tmp[bi] = NEG_INF;
      th = bv;
    }
    float inv = 1.f / den;
    float* gr = gates + (size_t)row * HH;
#pragma unroll
    for (int c = 0; c < 16; ++c) gr[c] = (acc[c] >= th) ? e[c] * inv : 0.f;
  }
}

// ---------------- fp32 tiled GEMM: C(MxN) = A(MxK) @ B(KxN), all row-major ----------------
// 128x128 tile, BK=16, 256 threads, 8x8 microtile as 2x2 blocks of 4x4 (split layout).
__global__ __launch_bounds__(256) void sgemm128(const float* __restrict__ A,
                                                const float* __restrict__ B,
                                                float* __restrict__ C,
                                                int M, int N, int K) {
  __shared__ float As[16][132];  // [k][m], padded
  __shared__ float Bs[16][132];  // [k][n], padded
  const int tid = threadIdx.x;
  const int tx = tid & 15;
  const int ty = tid >> 4;
  const int m0 = blockIdx.y * 128;
  const int n0 = blockIdx.x * 128;
  const int am = tid >> 2;          // 0..63
  const int ak = (tid & 3) << 2;    // 0,4,8,12
  const int bk = tid >> 5;          // 0..7
  const int bn = (tid & 31) << 2;   // 0..124
  const float* Ap0 = A + (size_t)(m0 + am) * K + ak;
  const float* Ap1 = Ap0 + (size_t)64 * K;
  const float* Bp0 = B + (size_t)bk * N + n0 + bn;
  const float* Bp1 = Bp0 + (size_t)8 * N;
  float acc[2][2][4][4] = {};
  for (int k0 = 0; k0 < K; k0 += 16) {
    float4 a0 = *reinterpret_cast<const float4*>(Ap0 + k0);
    float4 a1 = *reinterpret_cast<const float4*>(Ap1 + k0);
    float4 b0 = *reinterpret_cast<const float4*>(Bp0 + (size_t)k0 * N);
    float4 b1 = *reinterpret_cast<const float4*>(Bp1 + (size_t)k0 * N);
    __syncthreads();
    As[ak+0][am] = a0.x; As[ak+1][am] = a0.y; As[ak+2][am] = a0.z; As[ak+3][am] = a0.w;
    As[ak+0][am+64] = a1.x; As[ak+1][am+64] = a1.y; As[ak+2][am+64] = a1.z; As[ak+3][am+64] = a1.w;
    *reinterpret_cast<float4*>(&Bs[bk][bn]) = b0;
    *reinterpret_cast<float4*>(&Bs[bk+8][bn]) = b1;
    __syncthreads();
#pragma unroll
    for (int k = 0; k < 16; ++k) {
      float4 a0v = *reinterpret_cast<const float4*>(&As[k][ty*4]);
      float4 a1v = *reinterpret_cast<const float4*>(&As[k][ty*4+64]);
      float4 b0v = *reinterpret_cast<const float4*>(&Bs[k][tx*4]);
      float4 b1v = *reinterpret_cast<const float4*>(&Bs[k][tx*4+64]);
      const float av[2][4] = {{a0v.x,a0v.y,a0v.z,a0v.w},{a1v.x,a1v.y,a1v.z,a1v.w}};
      const float bv[2][4] = {{b0v.x,b0v.y,b0v.z,b0v.w},{b1v.x,b1v.y,b1v.z,b1v.w}};
#pragma unroll
      for (int mb = 0; mb < 2; ++mb)
#pragma unroll
        for (int i = 0; i < 4; ++i)
#pragma unroll
          for (int nb = 0; nb < 2; ++nb)
#pragma unroll
            for (int j = 0; j < 4; ++j)
              acc[mb][nb][i][j] = fmaf(av[mb][i], bv[nb][j], acc[mb][nb][i][j]);
    }
  }
#pragma unroll
  for (int mb = 0; mb < 2; ++mb)
#pragma unroll
    for (int i = 0; i < 4; ++i) {
      const int m = m0 + mb*64 + ty*4 + i;
#pragma unroll
      for (int nb = 0; nb < 2; ++nb) {
        float4 v = make_float4(acc[mb][nb][i][0], acc[mb][nb][i][1],
                               acc[mb][nb][i][2], acc[mb][nb][i][3]);
        *reinterpret_cast<float4*>(&C[(size_t)m * N + (n0 + nb*64 + tx*4)]) = v;
      }
    }
}

// ---------------- flash attention (fp32), gate fused in epilogue ----------------
// One block = (b, h, 64-row Q tile). 256 threads as 16x16, 4x4 microtile.
// Online softmax entirely in registers (row state replicated across the 16 lanes
// that own the row); K LDS buffer is reused for P (stored TRANSPOSED [n][m] so
// the PV loop reads both P and V as single ds_read_b128).
__global__ __launch_bounds__(256) void attn_kernel(const float* __restrict__ qkv,
                                                   const float* __restrict__ gates,
                                                   float* __restrict__ ypre) {
  __shared__ float Qs[64][68];   // [d][m]
  __shared__ float KPs[64][68];  // K phase: [d][n]; P phase: [n][m] (transposed)
  __shared__ float Vs[64][64];   // [n][d]
  const int nQT = TT / 64;
  const int bid = blockIdx.x;
  const int qt = nQT - 1 - bid / (BB*HH);   // longest blocks first
  const int bh = bid % (BB*HH);
  const int b = bh / HH;
  const int h = bh % HH;
  const int tid = threadIdx.x;
  const int tx = tid & 15;
  const int ty = tid >> 4;
  const size_t rs = 3 * DD;
  const float* qbase = qkv + ((size_t)(b*TT + qt*64)) * rs + h*DH;
  const float* kbase = qkv + ((size_t)b*TT) * rs + DD + h*DH;
  const float* vbase = qkv + ((size_t)b*TT) * rs + 2*DD + h*DH;
  const int sm = tid >> 2;   // staging row 0..63
  const int sg = tid & 3;    // staging float4 group
  {
    const float* src = qbase + (size_t)sm * rs;
#pragma unroll
    for (int u = 0; u < 4; ++u) {
      const int c = (sg + 4*u) * 4;
      float4 v = *reinterpret_cast<const float4*>(src + c);
      Qs[c+0][sm] = v.x; Qs[c+1][sm] = v.y; Qs[c+2][sm] = v.z; Qs[c+3][sm] = v.w;
    }
  }
  float oacc[4][4] = {};
  float rowM[4], rowL[4];
#pragma unroll
  for (int i = 0; i < 4; ++i) { rowM[i] = NEG_INF; rowL[i] = 0.f; }

  for (int jt = 0; jt <= qt; ++jt) {
    const float* ksrc = kbase + (size_t)(jt*64 + sm) * rs;
    const float* vsrc = vbase + (size_t)(jt*64 + sm) * rs;
    // issue global loads BEFORE the barrier so HBM/L2 latency overlaps the
    // tail of the previous PV phase (and Q staging on iter 0)
    float4 kreg[4], vreg[4];
#pragma unroll
    for (int u = 0; u < 4; ++u) {
      const int c = (sg + 4*u) * 4;
      kreg[u] = *reinterpret_cast<const float4*>(ksrc + c);
      vreg[u] = *reinterpret_cast<const float4*>(vsrc + c);
    }
    __syncthreads();   // previous PV done (and Q staged, first iter)
#pragma unroll
    for (int u = 0; u < 4; ++u) {
      const int c = (sg + 4*u) * 4;
      KPs[c+0][sm] = kreg[u].x; KPs[c+1][sm] = kreg[u].y;
      KPs[c+2][sm] = kreg[u].z; KPs[c+3][sm] = kreg[u].w;
      *reinterpret_cast<float4*>(&Vs[sm][c]) = vreg[u];
    }
    __syncthreads();
    // S = Q^T K  (4x4 per thread)
    float s[4][4] = {};
#pragma unroll 8
    for (int d = 0; d < 64; ++d) {
      float4 qv = *reinterpret_cast<const float4*>(&Qs[d][ty*4]);
      float4 kv = *reinterpret_cast<const float4*>(&KPs[d][tx*4]);
      const float qa[4] = {qv.x,qv.y,qv.z,qv.w};
      const float ka[4] = {kv.x,kv.y,kv.z,kv.w};
#pragma unroll
      for (int i = 0; i < 4; ++i)
#pragma unroll
        for (int j = 0; j < 4; ++j)
          s[i][j] = fmaf(qa[i], ka[j], s[i][j]);
    }
    __syncthreads();   // everyone finished reading K; KPs can be reused for P
    // scale + causal mask + in-register online softmax
    float p[4][4];
    float corr[4];
#pragma unroll
    for (int i = 0; i < 4; ++i) {
      const int qidx = qt*64 + ty*4 + i;
      float tmax = NEG_INF;
#pragma unroll
      for (int j = 0; j < 4; ++j) {
        const int kidx = jt*64 + tx*4 + j;
        float sv = s[i][j] * 0.125f;
        if (kidx > qidx) sv = NEG_INF;
        s[i][j] = sv;
        tmax = fmaxf(tmax, sv);
      }
      tmax = fmaxf(tmax, __shfl_xor(tmax, 1));
      tmax = fmaxf(tmax, __shfl_xor(tmax, 2));
      tmax = fmaxf(tmax, __shfl_xor(tmax, 4));
      tmax = fmaxf(tmax, __shfl_xor(tmax, 8));
      const float mnew = fmaxf(rowM[i], tmax);
      corr[i] = __expf(rowM[i] - mnew);
      float tsum = 0.f;
#pragma unroll
      for (int j = 0; j < 4; ++j) {
        p[i][j] = __expf(s[i][j] - mnew);
        tsum += p[i][j];
      }
      tsum += __shfl_xor(tsum, 1);
      tsum += __shfl_xor(tsum, 2);
      tsum += __shfl_xor(tsum, 4);
      tsum += __shfl_xor(tsum, 8);
      rowL[i] = rowL[i] * corr[i] + tsum;
      rowM[i] = mnew;
    }
    // store P TRANSPOSED: KPs[n][m] = P(m, n); contiguous-in-m float4 per j
#pragma unroll
    for (int j = 0; j < 4; ++j) {
      float4 v = make_float4(p[0][j], p[1][j], p[2][j], p[3][j]);
      *reinterpret_cast<float4*>(&KPs[tx*4+j][ty*4]) = v;
    }
#pragma unroll
    for (int i = 0; i < 4; ++i)
#pragma unroll
      for (int j = 0; j < 4; ++j)
        oacc[i][j] *= corr[i];
    __syncthreads();   // P visible to all
    // O += P V : per n, read P[n][m..m+3] (b128 broadcast) and V[n][d..d+3] (b128)
#pragma unroll 4
    for (int n = 0; n < 64; ++n) {
      float4 vv = *reinterpret_cast<const float4*>(&Vs[n][tx*4]);
      float4 pv = *reinterpret_cast<const float4*>(&KPs[n][ty*4]);
      const float va[4] = {vv.x, vv.y, vv.z, vv.w};
      const float pa[4] = {pv.x, pv.y, pv.z, pv.w};
#pragma unroll
      for (int i = 0; i < 4; ++i)
#pragma unroll
        for (int j = 0; j < 4; ++j)
          oacc[i][j] = fmaf(pa[i], va[j], oacc[i][j]);
    }
  }
  // epilogue: normalize + gate, write ypre
#pragma unroll
  for (int i = 0; i < 4; ++i) {
    const int t = qt*64 + ty*4 + i;
    const float g = gates[((size_t)(b*TT + t)) * HH + h];
    const float sc = g / rowL[i];
    float4 v = make_float4(oacc[i][0]*sc, oacc[i][1]*sc, oacc[i][2]*sc, oacc[i][3]*sc);
    *reinterpret_cast<float4*>(&ypre[((size_t)(b*TT + t)) * DD + h*DH + tx*4]) = v;
  }
}

extern "C" void kernel_launch(void* const* d_in, const int* in_sizes, int n_in,
                              void* d_out, int out_size, void* d_ws, size_t ws_size,
                              hipStream_t stream) {
  (void)in_sizes; (void)n_in; (void)out_size; (void)ws_size;
  const float* x    = (const float*)d_in[0];
  const float* Wqkv = (const float*)d_in[1];
  const float* Wr   = (const float*)d_in[2];
  const float* Wo   = (const float*)d_in[3];
  float* out = (float*)d_out;
  float* ws = (float*)d_ws;
  float* qkv   = ws;                              // BTOT * 3*DD floats (48 MB)
  float* gates = qkv + (size_t)BTOT * 3 * DD;     // BTOT * HH floats
  float* ypre  = gates + (size_t)BTOT * HH;       // BTOT * DD floats (16 MB)

  router_kernel<<<BTOT, 64, 0, stream>>>(x, Wr, gates);
  sgemm128<<<dim3(3*DD/128, BTOT/128), 256, 0, stream>>>(x, Wqkv, qkv, BTOT, 3*DD, DD);
  attn_kernel<<<(TT/64)*BB*HH, 256, 0, stream>>>(qkv, gates, ypre);
  sgemm128<<<dim3(DD/128, BTOT/128), 256, 0, stream>>>(ypre, Wo, out, BTOT, DD, DD);
}

// Round 8
// 370.264 us; speedup vs baseline: 2.1405x; 2.1405x over previous
//
#include <hip/hip_runtime.h>
#include <math.h>

#define BB 2
#define TT 2048
#define DD 1024
#define HH 16
#define DH 64
#define BTOT (BB*TT)
#define NEG_INF (-1e30f)
#define ATTN_MFMA 1

typedef _Float16 half8 __attribute__((ext_vector_type(8)));
typedef _Float16 half4 __attribute__((ext_vector_type(4)));
typedef float floatx4 __attribute__((ext_vector_type(4)));

// ---------------- split fp32 -> fp16 hi/lo (elementwise) ----------------
__global__ __launch_bounds__(256) void split_f32(const float* __restrict__ in,
                                                 _Float16* __restrict__ hi,
                                                 _Float16* __restrict__ lo,
                                                 int n4) {
  int idx = blockIdx.x * 256 + threadIdx.x;
  const int stride = gridDim.x * 256;
  for (; idx < n4; idx += stride) {
    float4 v = reinterpret_cast<const float4*>(in)[idx];
    half4 hv, lv;
    hv[0] = (_Float16)v.x; lv[0] = (_Float16)(v.x - (float)hv[0]);
    hv[1] = (_Float16)v.y; lv[1] = (_Float16)(v.y - (float)hv[1]);
    hv[2] = (_Float16)v.z; lv[2] = (_Float16)(v.z - (float)hv[2]);
    hv[3] = (_Float16)v.w; lv[3] = (_Float16)(v.w - (float)hv[3]);
    reinterpret_cast<half4*>(hi)[idx] = hv;
    reinterpret_cast<half4*>(lo)[idx] = lv;
  }
}

// ---------------- transpose + split: W[K][N] fp32 -> Wt_hi/lo[N][K] fp16 ----------------
__global__ __launch_bounds__(256) void wsplit_t(const float* __restrict__ W,
                                                _Float16* __restrict__ Wth,
                                                _Float16* __restrict__ Wtl,
                                                int K, int N) {
  __shared__ float buf[64][65];
  const int tid = threadIdx.x;
  const int k0 = blockIdx.y * 64;
  const int n0 = blockIdx.x * 64;
  const int rr = tid >> 4;          // 0..15
  const int cc = (tid & 15) * 4;    // 0..60
#pragma unroll
  for (int p = 0; p < 4; ++p) {
    const int r = rr + p * 16;
    float4 v = *reinterpret_cast<const float4*>(&W[(size_t)(k0 + r) * N + n0 + cc]);
    buf[r][cc+0] = v.x; buf[r][cc+1] = v.y; buf[r][cc+2] = v.z; buf[r][cc+3] = v.w;
  }
  __syncthreads();
  const int tn = tid >> 2;
#pragma unroll
  for (int pp = 0; pp < 2; ++pp) {
    const int c2 = (tid & 3) + pp * 4;
    half8 hv, lv;
#pragma unroll
    for (int j = 0; j < 8; ++j) {
      float f = buf[c2*8 + j][tn];
      hv[j] = (_Float16)f;
      lv[j] = (_Float16)(f - (float)hv[j]);
    }
    *reinterpret_cast<half8*>(&Wth[(size_t)(n0 + tn) * K + k0 + c2*8]) = hv;
    *reinterpret_cast<half8*>(&Wtl[(size_t)(n0 + tn) * K + k0 + c2*8]) = lv;
  }
}

// ---------------- router: logits -> softmax probs -> top-4 gate ----------------
__global__ __launch_bounds__(64) void router_kernel(const float* __restrict__ x,
                                                    const float* __restrict__ Wr,
                                                    float* __restrict__ gates) {
  const int row = blockIdx.x;
  const int lane = threadIdx.x;
  const float* xr = x + (size_t)row * DD;
  float acc[16];
#pragma unroll
  for (int c = 0; c < 16; ++c) acc[c] = 0.f;
  for (int d = lane; d < DD; d += 64) {
    float xv = xr[d];
    const float4* wrow = reinterpret_cast<const float4*>(Wr + (size_t)d * HH);
#pragma unroll
    for (int g = 0; g < 4; ++g) {
      float4 w = wrow[g];
      acc[g*4+0] = fmaf(xv, w.x, acc[g*4+0]);
      acc[g*4+1] = fmaf(xv, w.y, acc[g*4+1]);
      acc[g*4+2] = fmaf(xv, w.z, acc[g*4+2]);
      acc[g*4+3] = fmaf(xv, w.w, acc[g*4+3]);
    }
  }
#pragma unroll
  for (int c = 0; c < 16; ++c) {
    float v = acc[c];
    v += __shfl_down(v, 32);
    v += __shfl_down(v, 16);
    v += __shfl_down(v, 8);
    v += __shfl_down(v, 4);
    v += __shfl_down(v, 2);
    v += __shfl_down(v, 1);
    acc[c] = v;
  }
  if (lane == 0) {
    float mx = acc[0];
#pragma unroll
    for (int c = 1; c < 16; ++c) mx = fmaxf(mx, acc[c]);
    float e[16]; float den = 0.f;
#pragma unroll
    for (int c = 0; c < 16; ++c) { e[c] = __expf(acc[c] - mx); den += e[c]; }
    float tmp[16];
#pragma unroll
    for (int c = 0; c < 16; ++c) tmp[c] = acc[c];
    float th = NEG_INF;
    for (int it = 0; it < 4; ++it) {
      float bv = NEG_INF; int bi = 0;
      for (int c = 0; c < 16; ++c) { if (tmp[c] > bv) { bv = tmp[c]; bi = c; } }
      tmp[bi] = NEG_INF;
      th = bv;
    }
    float inv = 1.f / den;
    float* gr = gates + (size_t)row * HH;
#pragma unroll
    for (int c = 0; c < 16; ++c) gr[c] = (acc[c] >= th) ? e[c] * inv : 0.f;
  }
}

// ---------------- split-fp16 MFMA GEMM ----------------
// C(MxN fp32) = A(MxK) @ B(KxN) where A given as hi/lo fp16 [M][K] and
// B given TRANSPOSED as hi/lo fp16 [N][K]. acc += Ah*Bh + Ah*Bl + Al*Bh.
// 128x128 tile, BK=32, 256 threads = 4 waves (2x2 of 64x64), 4x4 frags of 16x16x32.
__global__ __launch_bounds__(256) void hgemm_split(const _Float16* __restrict__ Ah,
                                                   const _Float16* __restrict__ Al,
                                                   const _Float16* __restrict__ Bth,
                                                   const _Float16* __restrict__ Btl,
                                                   float* __restrict__ C,
                                                   int M, int N, int K) {
  __shared__ _Float16 As[2][128][40];  // [hi/lo][m][k], rows padded to 40 (80B)
  __shared__ _Float16 Bs[2][128][40];  // [hi/lo][n][k]
  const int tid = threadIdx.x;
  const int lane = tid & 63;
  const int w = tid >> 6;
  const int wr = w >> 1, wc = w & 1;
  const int lr = lane & 15, lg = lane >> 4;
  const int m0 = blockIdx.y * 128, n0 = blockIdx.x * 128;
  const int srow = tid >> 2;        // 0..63
  const int schunk = (tid & 3) * 8; // halves offset: 0,8,16,24
  const _Float16* ApH = Ah + (size_t)(m0 + srow) * K + schunk;
  const _Float16* ApL = Al + (size_t)(m0 + srow) * K + schunk;
  const _Float16* BpH = Bth + (size_t)(n0 + srow) * K + schunk;
  const _Float16* BpL = Btl + (size_t)(n0 + srow) * K + schunk;
  const size_t rskip = (size_t)64 * K;

  floatx4 acc[4][4] = {};
  for (int k0 = 0; k0 < K; k0 += 32) {
    int4 a0h = *reinterpret_cast<const int4*>(ApH + k0);
    int4 a1h = *reinterpret_cast<const int4*>(ApH + rskip + k0);
    int4 a0l = *reinterpret_cast<const int4*>(ApL + k0);
    int4 a1l = *reinterpret_cast<const int4*>(ApL + rskip + k0);
    int4 b0h = *reinterpret_cast<const int4*>(BpH + k0);
    int4 b1h = *reinterpret_cast<const int4*>(BpH + rskip + k0);
    int4 b0l = *reinterpret_cast<const int4*>(BpL + k0);
    int4 b1l = *reinterpret_cast<const int4*>(BpL + rskip + k0);
    __syncthreads();   // previous iter's LDS reads complete
    *reinterpret_cast<int4*>(&As[0][srow][schunk])      = a0h;
    *reinterpret_cast<int4*>(&As[0][srow + 64][schunk]) = a1h;
    *reinterpret_cast<int4*>(&As[1][srow][schunk])      = a0l;
    *reinterpret_cast<int4*>(&As[1][srow + 64][schunk]) = a1l;
    *reinterpret_cast<int4*>(&Bs[0][srow][schunk])      = b0h;
    *reinterpret_cast<int4*>(&Bs[0][srow + 64][schunk]) = b1h;
    *reinterpret_cast<int4*>(&Bs[1][srow][schunk])      = b0l;
    *reinterpret_cast<int4*>(&Bs[1][srow + 64][schunk]) = b1l;
    __syncthreads();
    half8 af[2][4], bf[2][4];
#pragma unroll
    for (int mi = 0; mi < 4; ++mi) {
      af[0][mi] = *reinterpret_cast<const half8*>(&As[0][wr*64 + mi*16 + lr][lg*8]);
      af[1][mi] = *reinterpret_cast<const half8*>(&As[1][wr*64 + mi*16 + lr][lg*8]);
    }
#pragma unroll
    for (int ni = 0; ni < 4; ++ni) {
      bf[0][ni] = *reinterpret_cast<const half8*>(&Bs[0][wc*64 + ni*16 + lr][lg*8]);
      bf[1][ni] = *reinterpret_cast<const half8*>(&Bs[1][wc*64 + ni*16 + lr][lg*8]);
    }
#pragma unroll
    for (int mi = 0; mi < 4; ++mi)
#pragma unroll
      for (int ni = 0; ni < 4; ++ni) {
        acc[mi][ni] = __builtin_amdgcn_mfma_f32_16x16x32_f16(af[0][mi], bf[0][ni], acc[mi][ni], 0, 0, 0);
        acc[mi][ni] = __builtin_amdgcn_mfma_f32_16x16x32_f16(af[0][mi], bf[1][ni], acc[mi][ni], 0, 0, 0);
        acc[mi][ni] = __builtin_amdgcn_mfma_f32_16x16x32_f16(af[1][mi], bf[0][ni], acc[mi][ni], 0, 0, 0);
      }
  }
  // C/D layout: col = lane&15, row = (lane>>4)*4 + reg (m89-verified)
#pragma unroll
  for (int mi = 0; mi < 4; ++mi)
#pragma unroll
    for (int ni = 0; ni < 4; ++ni) {
      const int n = n0 + wc*64 + ni*16 + lr;
#pragma unroll
      for (int r = 0; r < 4; ++r) {
        const int m = m0 + wr*64 + mi*16 + lg*4 + r;
        C[(size_t)m * N + n] = acc[mi][ni][r];
      }
    }
}

// ---------------- MFMA flash attention (split-fp16), gate fused ----------------
// 4 waves/block; wave wv owns Q rows qt*64+wv*16..+15. Q frags in registers.
// K staged [n][d] hi/lo; V staged transposed [d][n] hi/lo; P written hi/lo to
// this wave's own LDS rows (same-wave RAW only -> no extra barrier; DS ops
// from one wave complete in issue order).
__global__ __launch_bounds__(256) void attn_mfma(const float* __restrict__ qkv,
                                                 const float* __restrict__ gates,
                                                 _Float16* __restrict__ yhi,
                                                 _Float16* __restrict__ ylo) {
  __shared__ _Float16 Ksh[64][68], Ksl[64][68];   // K: [n][d]
  __shared__ _Float16 Vth[64][68], Vtl[64][68];   // V^T: [d][n]
  __shared__ _Float16 Psh[64][68], Psl[64][68];   // P: [m][n]
  const int nQT = TT / 64;
  const int bid = blockIdx.x;
  const int qt = nQT - 1 - bid / (BB*HH);   // longest blocks first
  const int bh = bid % (BB*HH);
  const int b = bh / HH, h = bh % HH;
  const int tid = threadIdx.x;
  const int lane = tid & 63;
  const int wv = tid >> 6;
  const int lr = lane & 15;
  const int lg = lane >> 4;
  const size_t rs = 3 * DD;
  const float* kbase = qkv + (size_t)b*TT*rs + DD + h*DH;
  const float* vbase = qkv + (size_t)b*TT*rs + 2*DD + h*DH;

  // Q fragments (hi/lo): row = qt*64+wv*16+lr, k = c*32 + lg*8 + j
  half8 qfh[2], qfl[2];
  {
    const float* qrow = qkv + (size_t)(b*TT + qt*64 + wv*16 + lr) * rs + h*DH + lg*8;
#pragma unroll
    for (int c = 0; c < 2; ++c) {
      float4 v0 = *reinterpret_cast<const float4*>(qrow + c*32);
      float4 v1 = *reinterpret_cast<const float4*>(qrow + c*32 + 4);
      const float f[8] = {v0.x,v0.y,v0.z,v0.w,v1.x,v1.y,v1.z,v1.w};
#pragma unroll
      for (int j = 0; j < 8; ++j) {
        qfh[c][j] = (_Float16)f[j];
        qfl[c][j] = (_Float16)(f[j] - (float)qfh[c][j]);
      }
    }
  }
  floatx4 oacc[4] = {};   // [dfrag]; row m=lg*4+r, col d=dfrag*16+lr
  float rowM[4], rowL[4];
#pragma unroll
  for (int r = 0; r < 4; ++r) { rowM[r] = NEG_INF; rowL[r] = 0.f; }

  const int sm = tid >> 2;   // staging row
  const int sg = tid & 3;

  for (int jt = 0; jt <= qt; ++jt) {
    const float* ksrc = kbase + (size_t)(jt*64 + sm) * rs;
    const float* vsrc = vbase + (size_t)(jt*64 + sm) * rs;
    float4 kreg[4], vreg[4];
#pragma unroll
    for (int u = 0; u < 4; ++u) {
      const int c = (sg + 4*u) * 4;
      kreg[u] = *reinterpret_cast<const float4*>(ksrc + c);
      vreg[u] = *reinterpret_cast<const float4*>(vsrc + c);
    }
    __syncthreads();   // prior iter's frag reads of Ks/Vt complete
#pragma unroll
    for (int u = 0; u < 4; ++u) {
      const int c = (sg + 4*u) * 4;
      const float kf[4] = {kreg[u].x, kreg[u].y, kreg[u].z, kreg[u].w};
      half4 kh, kl;
#pragma unroll
      for (int j = 0; j < 4; ++j) {
        kh[j] = (_Float16)kf[j];
        kl[j] = (_Float16)(kf[j] - (float)kh[j]);
      }
      *reinterpret_cast<half4*>(&Ksh[sm][c]) = kh;
      *reinterpret_cast<half4*>(&Ksl[sm][c]) = kl;
      const float vf[4] = {vreg[u].x, vreg[u].y, vreg[u].z, vreg[u].w};
#pragma unroll
      for (int j = 0; j < 4; ++j) {
        _Float16 vh = (_Float16)vf[j];
        Vth[c+j][sm] = vh;
        Vtl[c+j][sm] = (_Float16)(vf[j] - (float)vh);
      }
    }
    __syncthreads();
    // S = Q K^T
    floatx4 sacc[4] = {};
#pragma unroll
    for (int c = 0; c < 2; ++c)
#pragma unroll
      for (int nf = 0; nf < 4; ++nf) {
        half8 kbh = *reinterpret_cast<const half8*>(&Ksh[nf*16 + lr][c*32 + lg*8]);
        half8 kbl = *reinterpret_cast<const half8*>(&Ksl[nf*16 + lr][c*32 + lg*8]);
        sacc[nf] = __builtin_amdgcn_mfma_f32_16x16x32_f16(qfh[c], kbh, sacc[nf], 0, 0, 0);
        sacc[nf] = __builtin_amdgcn_mfma_f32_16x16x32_f16(qfh[c], kbl, sacc[nf], 0, 0, 0);
        sacc[nf] = __builtin_amdgcn_mfma_f32_16x16x32_f16(qfl[c], kbh, sacc[nf], 0, 0, 0);
      }
    // online softmax in C/D layout (row replicated across the 16 lr-lanes)
    float p[4][4];   // [nf][r]
    float corr[4];
#pragma unroll
    for (int r = 0; r < 4; ++r) {
      const int qidx = qt*64 + wv*16 + lg*4 + r;
      float tmax = NEG_INF;
#pragma unroll
      for (int nf = 0; nf < 4; ++nf) {
        const int kidx = jt*64 + nf*16 + lr;
        float sv = sacc[nf][r] * 0.125f;
        if (kidx > qidx) sv = NEG_INF;
        p[nf][r] = sv;
        tmax = fmaxf(tmax, sv);
      }
      tmax = fmaxf(tmax, __shfl_xor(tmax, 1));
      tmax = fmaxf(tmax, __shfl_xor(tmax, 2));
      tmax = fmaxf(tmax, __shfl_xor(tmax, 4));
      tmax = fmaxf(tmax, __shfl_xor(tmax, 8));
      const float mnew = fmaxf(rowM[r], tmax);
      corr[r] = __expf(rowM[r] - mnew);
      float tsum = 0.f;
#pragma unroll
      for (int nf = 0; nf < 4; ++nf) {
        const float pv = __expf(p[nf][r] - mnew);
        p[nf][r] = pv;
        tsum += pv;
      }
      tsum += __shfl_xor(tsum, 1);
      tsum += __shfl_xor(tsum, 2);
      tsum += __shfl_xor(tsum, 4);
      tsum += __shfl_xor(tsum, 8);
      rowL[r] = rowL[r] * corr[r] + tsum;
      rowM[r] = mnew;
    }
    // P -> LDS (hi/lo), this wave's rows only
#pragma unroll
    for (int nf = 0; nf < 4; ++nf)
#pragma unroll
      for (int r = 0; r < 4; ++r) {
        const _Float16 ph = (_Float16)p[nf][r];
        Psh[wv*16 + lg*4 + r][nf*16 + lr] = ph;
        Psl[wv*16 + lg*4 + r][nf*16 + lr] = (_Float16)(p[nf][r] - (float)ph);
      }
    // rescale O
#pragma unroll
    for (int df = 0; df < 4; ++df)
#pragma unroll
      for (int r = 0; r < 4; ++r)
        oacc[df][r] *= corr[r];
    // O += P V
#pragma unroll
    for (int c = 0; c < 2; ++c) {
      half8 pah = *reinterpret_cast<const half8*>(&Psh[wv*16 + lr][c*32 + lg*8]);
      half8 pal = *reinterpret_cast<const half8*>(&Psl[wv*16 + lr][c*32 + lg*8]);
#pragma unroll
      for (int df = 0; df < 4; ++df) {
        half8 vbh = *reinterpret_cast<const half8*>(&Vth[df*16 + lr][c*32 + lg*8]);
        half8 vbl = *reinterpret_cast<const half8*>(&Vtl[df*16 + lr][c*32 + lg*8]);
        oacc[df] = __builtin_amdgcn_mfma_f32_16x16x32_f16(pah, vbh, oacc[df], 0, 0, 0);
        oacc[df] = __builtin_amdgcn_mfma_f32_16x16x32_f16(pah, vbl, oacc[df], 0, 0, 0);
        oacc[df] = __builtin_amdgcn_mfma_f32_16x16x32_f16(pal, vbh, oacc[df], 0, 0, 0);
      }
    }
  }
  // epilogue: normalize + gate, emit fp16 hi/lo split of ypre
#pragma unroll
  for (int r = 0; r < 4; ++r) {
    const int t = qt*64 + wv*16 + lg*4 + r;
    const float g = gates[((size_t)(b*TT + t)) * HH + h];
    const float sc = g / rowL[r];
#pragma unroll
    for (int df = 0; df < 4; ++df) {
      const float v = oacc[df][r] * sc;
      const _Float16 vh = (_Float16)v;
      const size_t off = ((size_t)(b*TT + t)) * DD + h*DH + df*16 + lr;
      yhi[off] = vh;
      ylo[off] = (_Float16)(v - (float)vh);
    }
  }
}

// ---------------- fp32 flash attention (fallback, ATTN_MFMA=0) ----------------
__global__ __launch_bounds__(256) void attn_kernel(const float* __restrict__ qkv,
                                                   const float* __restrict__ gates,
                                                   _Float16* __restrict__ yhi,
                                                   _Float16* __restrict__ ylo) {
  __shared__ float Qs[64][68];
  __shared__ float KPs[64][68];
  __shared__ float Vs[64][64];
  const int nQT = TT / 64;
  const int bid = blockIdx.x;
  const int qt = nQT - 1 - bid / (BB*HH);
  const int bh = bid % (BB*HH);
  const int b = bh / HH;
  const int h = bh % HH;
  const int tid = threadIdx.x;
  const int tx = tid & 15;
  const int ty = tid >> 4;
  const size_t rs = 3 * DD;
  const float* qbase = qkv + ((size_t)(b*TT + qt*64)) * rs + h*DH;
  const float* kbase = qkv + ((size_t)b*TT) * rs + DD + h*DH;
  const float* vbase = qkv + ((size_t)b*TT) * rs + 2*DD + h*DH;
  const int sm = tid >> 2;
  const int sg = tid & 3;
  {
    const float* src = qbase + (size_t)sm * rs;
#pragma unroll
    for (int u = 0; u < 4; ++u) {
      const int c = (sg + 4*u) * 4;
      float4 v = *reinterpret_cast<const float4*>(src + c);
      Qs[c+0][sm] = v.x; Qs[c+1][sm] = v.y; Qs[c+2][sm] = v.z; Qs[c+3][sm] = v.w;
    }
  }
  float oacc[4][4] = {};
  float rowM[4], rowL[4];
#pragma unroll
  for (int i = 0; i < 4; ++i) { rowM[i] = NEG_INF; rowL[i] = 0.f; }
  for (int jt = 0; jt <= qt; ++jt) {
    const float* ksrc = kbase + (size_t)(jt*64 + sm) * rs;
    const float* vsrc = vbase + (size_t)(jt*64 + sm) * rs;
    float4 kreg[4], vreg[4];
#pragma unroll
    for (int u = 0; u < 4; ++u) {
      const int c = (sg + 4*u) * 4;
      kreg[u] = *reinterpret_cast<const float4*>(ksrc + c);
      vreg[u] = *reinterpret_cast<const float4*>(vsrc + c);
    }
    __syncthreads();
#pragma unroll
    for (int u = 0; u < 4; ++u) {
      const int c = (sg + 4*u) * 4;
      KPs[c+0][sm] = kreg[u].x; KPs[c+1][sm] = kreg[u].y;
      KPs[c+2][sm] = kreg[u].z; KPs[c+3][sm] = kreg[u].w;
      *reinterpret_cast<float4*>(&Vs[sm][c]) = vreg[u];
    }
    __syncthreads();
    float s[4][4] = {};
#pragma unroll 8
    for (int d = 0; d < 64; ++d) {
      float4 qv = *reinterpret_cast<const float4*>(&Qs[d][ty*4]);
      float4 kv = *reinterpret_cast<const float4*>(&KPs[d][tx*4]);
      const float qa[4] = {qv.x,qv.y,qv.z,qv.w};
      const float ka[4] = {kv.x,kv.y,kv.z,kv.w};
#pragma unroll
      for (int i = 0; i < 4; ++i)
#pragma unroll
        for (int j = 0; j < 4; ++j)
          s[i][j] = fmaf(qa[i], ka[j], s[i][j]);
    }
    __syncthreads();
    float p[4][4];
    float corr[4];
#pragma unroll
    for (int i = 0; i < 4; ++i) {
      const int qidx = qt*64 + ty*4 + i;
      float tmax = NEG_INF;
#pragma unroll
      for (int j = 0; j < 4; ++j) {
        const int kidx = jt*64 + tx*4 + j;
        float sv = s[i][j] * 0.125f;
        if (kidx > qidx) sv = NEG_INF;
        s[i][j] = sv;
        tmax = fmaxf(tmax, sv);
      }
      tmax = fmaxf(tmax, __shfl_xor(tmax, 1));
      tmax = fmaxf(tmax, __shfl_xor(tmax, 2));
      tmax = fmaxf(tmax, __shfl_xor(tmax, 4));
      tmax = fmaxf(tmax, __shfl_xor(tmax, 8));
      const float mnew = fmaxf(rowM[i], tmax);
      corr[i] = __expf(rowM[i] - mnew);
      float tsum = 0.f;
#pragma unroll
      for (int j = 0; j < 4; ++j) {
        p[i][j] = __expf(s[i][j] - mnew);
        tsum += p[i][j];
      }
      tsum += __shfl_xor(tsum, 1);
      tsum += __shfl_xor(tsum, 2);
      tsum += __shfl_xor(tsum, 4);
      tsum += __shfl_xor(tsum, 8);
      rowL[i] = rowL[i] * corr[i] + tsum;
      rowM[i] = mnew;
    }
#pragma unroll
    for (int i = 0; i < 4; ++i) {
      float4 v = make_float4(p[i][0], p[i][1], p[i][2], p[i][3]);
      *reinterpret_cast<float4*>(&KPs[ty*4+i][tx*4]) = v;
    }
#pragma unroll
    for (int i = 0; i < 4; ++i)
#pragma unroll
      for (int j = 0; j < 4; ++j)
        oacc[i][j] *= corr[i];
    __syncthreads();
#pragma unroll 4
    for (int n = 0; n < 64; ++n) {
      float4 vv = *reinterpret_cast<const float4*>(&Vs[n][tx*4]);
      const float va[4] = {vv.x, vv.y, vv.z, vv.w};
#pragma unroll
      for (int i = 0; i < 4; ++i) {
        const float pm = KPs[ty*4+i][n];
#pragma unroll
        for (int j = 0; j < 4; ++j)
          oacc[i][j] = fmaf(pm, va[j], oacc[i][j]);
      }
    }
  }
#pragma unroll
  for (int i = 0; i < 4; ++i) {
    const int t = qt*64 + ty*4 + i;
    const float g = gates[((size_t)(b*TT + t)) * HH + h];
    const float sc = g / rowL[i];
    half4 hv, lv;
#pragma unroll
    for (int j = 0; j < 4; ++j) {
      float v = oacc[i][j] * sc;
      hv[j] = (_Float16)v;
      lv[j] = (_Float16)(v - (float)hv[j]);
    }
    const size_t off = ((size_t)(b*TT + t)) * DD + h*DH + tx*4;
    *reinterpret_cast<half4*>(&yhi[off]) = hv;
    *reinterpret_cast<half4*>(&ylo[off]) = lv;
  }
}

extern "C" void kernel_launch(void* const* d_in, const int* in_sizes, int n_in,
                              void* d_out, int out_size, void* d_ws, size_t ws_size,
                              hipStream_t stream) {
  (void)in_sizes; (void)n_in; (void)out_size; (void)ws_size;
  const float* x    = (const float*)d_in[0];
  const float* Wqkv = (const float*)d_in[1];
  const float* Wr   = (const float*)d_in[2];
  const float* Wo   = (const float*)d_in[3];
  float* out = (float*)d_out;

  float* ws = (float*)d_ws;
  float* qkv   = ws;                               // 4096*3072 fp32 (50.3 MB)
  float* gates = qkv + (size_t)BTOT * 3 * DD;      // 4096*16 fp32
  _Float16* x_hi = (_Float16*)(gates + (size_t)BTOT * HH);
  _Float16* x_lo = x_hi + (size_t)BTOT * DD;
  _Float16* Wqh  = x_lo + (size_t)BTOT * DD;
  _Float16* Wql  = Wqh + (size_t)DD * 3 * DD;
  _Float16* Woh  = Wql + (size_t)DD * 3 * DD;
  _Float16* Wol  = Woh + (size_t)DD * DD;
  // ypre hi/lo alias x_hi/x_lo (x split is dead after the qkv GEMM)
  _Float16* yhi = x_hi;
  _Float16* ylo = x_lo;

  split_f32<<<1024, 256, 0, stream>>>(x, x_hi, x_lo, BTOT * DD / 4);
  wsplit_t<<<dim3(3*DD/64, DD/64), 256, 0, stream>>>(Wqkv, Wqh, Wql, DD, 3*DD);
  wsplit_t<<<dim3(DD/64, DD/64), 256, 0, stream>>>(Wo, Woh, Wol, DD, DD);
  router_kernel<<<BTOT, 64, 0, stream>>>(x, Wr, gates);
  hgemm_split<<<dim3(3*DD/128, BTOT/128), 256, 0, stream>>>(x_hi, x_lo, Wqh, Wql, qkv, BTOT, 3*DD, DD);
#if ATTN_MFMA
  attn_mfma<<<(TT/64)*BB*HH, 256, 0, stream>>>(qkv, gates, yhi, ylo);
#else
  attn_kernel<<<(TT/64)*BB*HH, 256, 0, stream>>>(qkv, gates, yhi, ylo);
#endif
  hgemm_split<<<dim3(DD/128, BTOT/128), 256, 0, stream>>>(yhi, ylo, Woh, Wol, out, BTOT, DD, DD);
}

// Round 10
// 349.979 us; speedup vs baseline: 2.2646x; 1.0580x over previous
//
#include <hip/hip_runtime.h>
#include <math.h>

#define BB 2
#define TT 2048
#define DD 1024
#define HH 16
#define DH 64
#define BTOT (BB*TT)
#define NEG_INF (-1e30f)
#define V_LO 0   // 1 = restore V hi/lo split in PV (fallback for bisection)

typedef _Float16 half8 __attribute__((ext_vector_type(8)));
typedef _Float16 half4 __attribute__((ext_vector_type(4)));
typedef float floatx4 __attribute__((ext_vector_type(4)));

// ---------------- split fp32 -> fp16 hi/lo (elementwise) ----------------
__global__ __launch_bounds__(256) void split_f32(const float* __restrict__ in,
                                                 _Float16* __restrict__ hi,
                                                 _Float16* __restrict__ lo,
                                                 int n4) {
  int idx = blockIdx.x * 256 + threadIdx.x;
  const int stride = gridDim.x * 256;
  for (; idx < n4; idx += stride) {
    float4 v = reinterpret_cast<const float4*>(in)[idx];
    half4 hv, lv;
    hv[0] = (_Float16)v.x; lv[0] = (_Float16)(v.x - (float)hv[0]);
    hv[1] = (_Float16)v.y; lv[1] = (_Float16)(v.y - (float)hv[1]);
    hv[2] = (_Float16)v.z; lv[2] = (_Float16)(v.z - (float)hv[2]);
    hv[3] = (_Float16)v.w; lv[3] = (_Float16)(v.w - (float)hv[3]);
    reinterpret_cast<half4*>(hi)[idx] = hv;
    reinterpret_cast<half4*>(lo)[idx] = lv;
  }
}

// ---------------- transpose + split: W[K][N] fp32 -> Wt_hi/lo[N][K] fp16 ----------------
__global__ __launch_bounds__(256) void wsplit_t(const float* __restrict__ W,
                                                _Float16* __restrict__ Wth,
                                                _Float16* __restrict__ Wtl,
                                                int K, int N) {
  __shared__ float buf[64][65];
  const int tid = threadIdx.x;
  const int k0 = blockIdx.y * 64;
  const int n0 = blockIdx.x * 64;
  const int rr = tid >> 4;          // 0..15
  const int cc = (tid & 15) * 4;    // 0..60
#pragma unroll
  for (int p = 0; p < 4; ++p) {
    const int r = rr + p * 16;
    float4 v = *reinterpret_cast<const float4*>(&W[(size_t)(k0 + r) * N + n0 + cc]);
    buf[r][cc+0] = v.x; buf[r][cc+1] = v.y; buf[r][cc+2] = v.z; buf[r][cc+3] = v.w;
  }
  __syncthreads();
  const int tn = tid >> 2;
#pragma unroll
  for (int pp = 0; pp < 2; ++pp) {
    const int c2 = (tid & 3) + pp * 4;
    half8 hv, lv;
#pragma unroll
    for (int j = 0; j < 8; ++j) {
      float f = buf[c2*8 + j][tn];
      hv[j] = (_Float16)f;
      lv[j] = (_Float16)(f - (float)hv[j]);
    }
    *reinterpret_cast<half8*>(&Wth[(size_t)(n0 + tn) * K + k0 + c2*8]) = hv;
    *reinterpret_cast<half8*>(&Wtl[(size_t)(n0 + tn) * K + k0 + c2*8]) = lv;
  }
}

// ---------------- router: logits -> softmax probs -> top-4 gate ----------------
__global__ __launch_bounds__(64) void router_kernel(const float* __restrict__ x,
                                                    const float* __restrict__ Wr,
                                                    float* __restrict__ gates) {
  const int row = blockIdx.x;
  const int lane = threadIdx.x;
  const float* xr = x + (size_t)row * DD;
  float acc[16];
#pragma unroll
  for (int c = 0; c < 16; ++c) acc[c] = 0.f;
  for (int d = lane; d < DD; d += 64) {
    float xv = xr[d];
    const float4* wrow = reinterpret_cast<const float4*>(Wr + (size_t)d * HH);
#pragma unroll
    for (int g = 0; g < 4; ++g) {
      float4 w = wrow[g];
      acc[g*4+0] = fmaf(xv, w.x, acc[g*4+0]);
      acc[g*4+1] = fmaf(xv, w.y, acc[g*4+1]);
      acc[g*4+2] = fmaf(xv, w.z, acc[g*4+2]);
      acc[g*4+3] = fmaf(xv, w.w, acc[g*4+3]);
    }
  }
#pragma unroll
  for (int c = 0; c < 16; ++c) {
    float v = acc[c];
    v += __shfl_down(v, 32);
    v += __shfl_down(v, 16);
    v += __shfl_down(v, 8);
    v += __shfl_down(v, 4);
    v += __shfl_down(v, 2);
    v += __shfl_down(v, 1);
    acc[c] = v;
  }
  if (lane == 0) {
    float mx = acc[0];
#pragma unroll
    for (int c = 1; c < 16; ++c) mx = fmaxf(mx, acc[c]);
    float e[16]; float den = 0.f;
#pragma unroll
    for (int c = 0; c < 16; ++c) { e[c] = __expf(acc[c] - mx); den += e[c]; }
    float tmp[16];
#pragma unroll
    for (int c = 0; c < 16; ++c) tmp[c] = acc[c];
    float th = NEG_INF;
    for (int it = 0; it < 4; ++it) {
      float bv = NEG_INF; int bi = 0;
      for (int c = 0; c < 16; ++c) { if (tmp[c] > bv) { bv = tmp[c]; bi = c; } }
      tmp[bi] = NEG_INF;
      th = bv;
    }
    float inv = 1.f / den;
    float* gr = gates + (size_t)row * HH;
#pragma unroll
    for (int c = 0; c < 16; ++c) gr[c] = (acc[c] >= th) ? e[c] * inv : 0.f;
  }
}

// ---------------- split-fp16 MFMA GEMM ----------------
// C(MxN) = A(MxK) @ B(KxN), A as hi/lo fp16 [M][K], B^T as hi/lo fp16 [N][K].
// acc += Ah*Bh + Ah*Bl + Al*Bh. 128x128 tile, BK=32, 4 waves, 4x4 16x16x32 frags.
// EMIT_HALF=true: epilogue emits fp16 hi/lo planes (Ch,Cl) instead of fp32 C.
template<bool EMIT_HALF>
__global__ __launch_bounds__(256) void hgemm_split(const _Float16* __restrict__ Ah,
                                                   const _Float16* __restrict__ Al,
                                                   const _Float16* __restrict__ Bth,
                                                   const _Float16* __restrict__ Btl,
                                                   float* __restrict__ C,
                                                   _Float16* __restrict__ Ch,
                                                   _Float16* __restrict__ Cl,
                                                   int M, int N, int K) {
  __shared__ _Float16 As[2][128][40];  // [hi/lo][m][k], rows padded to 40 (80B)
  __shared__ _Float16 Bs[2][128][40];  // [hi/lo][n][k]
  const int tid = threadIdx.x;
  const int lane = tid & 63;
  const int w = tid >> 6;
  const int wr = w >> 1, wc = w & 1;
  const int lr = lane & 15, lg = lane >> 4;
  const int m0 = blockIdx.y * 128, n0 = blockIdx.x * 128;
  const int srow = tid >> 2;        // 0..63
  const int schunk = (tid & 3) * 8; // halves offset: 0,8,16,24
  const _Float16* ApH = Ah + (size_t)(m0 + srow) * K + schunk;
  const _Float16* ApL = Al + (size_t)(m0 + srow) * K + schunk;
  const _Float16* BpH = Bth + (size_t)(n0 + srow) * K + schunk;
  const _Float16* BpL = Btl + (size_t)(n0 + srow) * K + schunk;
  const size_t rskip = (size_t)64 * K;

  floatx4 acc[4][4] = {};
  for (int k0 = 0; k0 < K; k0 += 32) {
    int4 a0h = *reinterpret_cast<const int4*>(ApH + k0);
    int4 a1h = *reinterpret_cast<const int4*>(ApH + rskip + k0);
    int4 a0l = *reinterpret_cast<const int4*>(ApL + k0);
    int4 a1l = *reinterpret_cast<const int4*>(ApL + rskip + k0);
    int4 b0h = *reinterpret_cast<const int4*>(BpH + k0);
    int4 b1h = *reinterpret_cast<const int4*>(BpH + rskip + k0);
    int4 b0l = *reinterpret_cast<const int4*>(BpL + k0);
    int4 b1l = *reinterpret_cast<const int4*>(BpL + rskip + k0);
    __syncthreads();   // previous iter's LDS reads complete
    *reinterpret_cast<int4*>(&As[0][srow][schunk])      = a0h;
    *reinterpret_cast<int4*>(&As[0][srow + 64][schunk]) = a1h;
    *reinterpret_cast<int4*>(&As[1][srow][schunk])      = a0l;
    *reinterpret_cast<int4*>(&As[1][srow + 64][schunk]) = a1l;
    *reinterpret_cast<int4*>(&Bs[0][srow][schunk])      = b0h;
    *reinterpret_cast<int4*>(&Bs[0][srow + 64][schunk]) = b1h;
    *reinterpret_cast<int4*>(&Bs[1][srow][schunk])      = b0l;
    *reinterpret_cast<int4*>(&Bs[1][srow + 64][schunk]) = b1l;
    __syncthreads();
    half8 af[2][4], bf[2][4];
#pragma unroll
    for (int mi = 0; mi < 4; ++mi) {
      af[0][mi] = *reinterpret_cast<const half8*>(&As[0][wr*64 + mi*16 + lr][lg*8]);
      af[1][mi] = *reinterpret_cast<const half8*>(&As[1][wr*64 + mi*16 + lr][lg*8]);
    }
#pragma unroll
    for (int ni = 0; ni < 4; ++ni) {
      bf[0][ni] = *reinterpret_cast<const half8*>(&Bs[0][wc*64 + ni*16 + lr][lg*8]);
      bf[1][ni] = *reinterpret_cast<const half8*>(&Bs[1][wc*64 + ni*16 + lr][lg*8]);
    }
#pragma unroll
    for (int mi = 0; mi < 4; ++mi)
#pragma unroll
      for (int ni = 0; ni < 4; ++ni) {
        acc[mi][ni] = __builtin_amdgcn_mfma_f32_16x16x32_f16(af[0][mi], bf[0][ni], acc[mi][ni], 0, 0, 0);
        acc[mi][ni] = __builtin_amdgcn_mfma_f32_16x16x32_f16(af[0][mi], bf[1][ni], acc[mi][ni], 0, 0, 0);
        acc[mi][ni] = __builtin_amdgcn_mfma_f32_16x16x32_f16(af[1][mi], bf[0][ni], acc[mi][ni], 0, 0, 0);
      }
  }
  // C/D layout: col = lane&15, row = (lane>>4)*4 + reg (m89-verified)
#pragma unroll
  for (int mi = 0; mi < 4; ++mi)
#pragma unroll
    for (int ni = 0; ni < 4; ++ni) {
      const int n = n0 + wc*64 + ni*16 + lr;
#pragma unroll
      for (int r = 0; r < 4; ++r) {
        const int m = m0 + wr*64 + mi*16 + lg*4 + r;
        const float v = acc[mi][ni][r];
        if (EMIT_HALF) {
          const _Float16 vh = (_Float16)v;
          Ch[(size_t)m * N + n] = vh;
          Cl[(size_t)m * N + n] = (_Float16)(v - (float)vh);
        } else {
          C[(size_t)m * N + n] = v;
        }
      }
    }
}

// ---------------- MFMA flash attention on pre-split fp16 qkv ----------------
// 4 waves/block; wave wv owns Q rows qt*64+wv*16..+15. Q hi/lo frags direct-loaded.
// K staged [n][d] hi/lo (pure copy); V staged transposed [d][n] HI-only (V_LO=0).
// P written hi/lo to this wave's own LDS rows (same-wave RAW -> no barrier).
__global__ __launch_bounds__(256) void attn_mfma(const _Float16* __restrict__ qkvh,
                                                 const _Float16* __restrict__ qkvl,
                                                 const float* __restrict__ gates,
                                                 _Float16* __restrict__ yhi,
                                                 _Float16* __restrict__ ylo) {
  __shared__ _Float16 Ksh[64][68], Ksl[64][68];   // K: [n][d]
  __shared__ _Float16 Vth[64][68];                // V^T: [d][n] (hi)
#if V_LO
  __shared__ _Float16 Vtl[64][68];
#endif
  __shared__ _Float16 Psh[64][68], Psl[64][68];   // P: [m][n]
  const int nQT = TT / 64;
  const int bid = blockIdx.x;
  const int qt = nQT - 1 - bid / (BB*HH);   // longest blocks first
  const int bh = bid % (BB*HH);
  const int b = bh / HH, h = bh % HH;
  const int tid = threadIdx.x;
  const int lane = tid & 63;
  const int wv = tid >> 6;
  const int lr = lane & 15;
  const int lg = lane >> 4;
  const size_t rs = 3 * DD;
  const _Float16* kbh = qkvh + (size_t)b*TT*rs + DD + h*DH;
  const _Float16* kbl = qkvl + (size_t)b*TT*rs + DD + h*DH;
  const _Float16* vbh = qkvh + (size_t)b*TT*rs + 2*DD + h*DH;
#if V_LO
  const _Float16* vbl = qkvl + (size_t)b*TT*rs + 2*DD + h*DH;
#endif

  // Q fragments hi/lo: row = qt*64+wv*16+lr, k = c*32 + lg*8 + j  (direct load)
  half8 qfh[2], qfl[2];
  {
    const _Float16* qrh = qkvh + (size_t)(b*TT + qt*64 + wv*16 + lr) * rs + h*DH + lg*8;
    const _Float16* qrl = qkvl + (size_t)(b*TT + qt*64 + wv*16 + lr) * rs + h*DH + lg*8;
#pragma unroll
    for (int c = 0; c < 2; ++c) {
      qfh[c] = *reinterpret_cast<const half8*>(qrh + c*32);
      qfl[c] = *reinterpret_cast<const half8*>(qrl + c*32);
    }
  }
  floatx4 oacc[4] = {};   // [dfrag]; row m=lg*4+r, col d=dfrag*16+lr
  float rowM[4], rowL[4];
#pragma unroll
  for (int r = 0; r < 4; ++r) { rowM[r] = NEG_INF; rowL[r] = 0.f; }

  const int sm = tid >> 2;   // staging row 0..63
  const int sg = tid & 3;    // staging col-chunk (16 halves each)

  for (int jt = 0; jt <= qt; ++jt) {
    const size_t roff = (size_t)(jt*64 + sm) * rs + sg*16;
    half8 kh0 = *reinterpret_cast<const half8*>(kbh + roff);
    half8 kh1 = *reinterpret_cast<const half8*>(kbh + roff + 8);
    half8 kl0 = *reinterpret_cast<const half8*>(kbl + roff);
    half8 kl1 = *reinterpret_cast<const half8*>(kbl + roff + 8);
    half8 vh0 = *reinterpret_cast<const half8*>(vbh + roff);
    half8 vh1 = *reinterpret_cast<const half8*>(vbh + roff + 8);
#if V_LO
    half8 vl0 = *reinterpret_cast<const half8*>(vbl + roff);
    half8 vl1 = *reinterpret_cast<const half8*>(vbl + roff + 8);
#endif
    __syncthreads();   // prior iter's frag reads complete
    *reinterpret_cast<half8*>(&Ksh[sm][sg*16])     = kh0;
    *reinterpret_cast<half8*>(&Ksh[sm][sg*16 + 8]) = kh1;
    *reinterpret_cast<half8*>(&Ksl[sm][sg*16])     = kl0;
    *reinterpret_cast<half8*>(&Ksl[sm][sg*16 + 8]) = kl1;
#pragma unroll
    for (int jj = 0; jj < 8; ++jj) {
      Vth[sg*16 + jj][sm]     = vh0[jj];
      Vth[sg*16 + 8 + jj][sm] = vh1[jj];
#if V_LO
      Vtl[sg*16 + jj][sm]     = vl0[jj];
      Vtl[sg*16 + 8 + jj][sm] = vl1[jj];
#endif
    }
    __syncthreads();
    // S = Q K^T  (3-term split)
    floatx4 sacc[4] = {};
#pragma unroll
    for (int c = 0; c < 2; ++c)
#pragma unroll
      for (int nf = 0; nf < 4; ++nf) {
        half8 kfh = *reinterpret_cast<const half8*>(&Ksh[nf*16 + lr][c*32 + lg*8]);
        half8 kfl = *reinterpret_cast<const half8*>(&Ksl[nf*16 + lr][c*32 + lg*8]);
        sacc[nf] = __builtin_amdgcn_mfma_f32_16x16x32_f16(qfh[c], kfh, sacc[nf], 0, 0, 0);
        sacc[nf] = __builtin_amdgcn_mfma_f32_16x16x32_f16(qfh[c], kfl, sacc[nf], 0, 0, 0);
        sacc[nf] = __builtin_amdgcn_mfma_f32_16x16x32_f16(qfl[c], kfh, sacc[nf], 0, 0, 0);
      }
    // online softmax in C/D layout (row replicated across the 16 lr-lanes)
    float p[4][4];   // [nf][r]
    float corr[4];
#pragma unroll
    for (int r = 0; r < 4; ++r) {
      const int qidx = qt*64 + wv*16 + lg*4 + r;
      float tmax = NEG_INF;
#pragma unroll
      for (int nf = 0; nf < 4; ++nf) {
        const int kidx = jt*64 + nf*16 + lr;
        float sv = sacc[nf][r] * 0.125f;
        if (kidx > qidx) sv = NEG_INF;
        p[nf][r] = sv;
        tmax = fmaxf(tmax, sv);
      }
      tmax = fmaxf(tmax, __shfl_xor(tmax, 1));
      tmax = fmaxf(tmax, __shfl_xor(tmax, 2));
      tmax = fmaxf(tmax, __shfl_xor(tmax, 4));
      tmax = fmaxf(tmax, __shfl_xor(tmax, 8));
      const float mnew = fmaxf(rowM[r], tmax);
      corr[r] = __expf(rowM[r] - mnew);
      float tsum = 0.f;
#pragma unroll
      for (int nf = 0; nf < 4; ++nf) {
        const float pv = __expf(p[nf][r] - mnew);
        p[nf][r] = pv;
        tsum += pv;
      }
      tsum += __shfl_xor(tsum, 1);
      tsum += __shfl_xor(tsum, 2);
      tsum += __shfl_xor(tsum, 4);
      tsum += __shfl_xor(tsum, 8);
      rowL[r] = rowL[r] * corr[r] + tsum;
      rowM[r] = mnew;
    }
    // P -> LDS (hi/lo), this wave's rows only
#pragma unroll
    for (int nf = 0; nf < 4; ++nf)
#pragma unroll
      for (int r = 0; r < 4; ++r) {
        const _Float16 ph = (_Float16)p[nf][r];
        Psh[wv*16 + lg*4 + r][nf*16 + lr] = ph;
        Psl[wv*16 + lg*4 + r][nf*16 + lr] = (_Float16)(p[nf][r] - (float)ph);
      }
    // rescale O
#pragma unroll
    for (int df = 0; df < 4; ++df)
#pragma unroll
      for (int r = 0; r < 4; ++r)
        oacc[df][r] *= corr[r];
    // O += P V
#pragma unroll
    for (int c = 0; c < 2; ++c) {
      half8 pah = *reinterpret_cast<const half8*>(&Psh[wv*16 + lr][c*32 + lg*8]);
      half8 pal = *reinterpret_cast<const half8*>(&Psl[wv*16 + lr][c*32 + lg*8]);
#pragma unroll
      for (int df = 0; df < 4; ++df) {
        half8 vfh = *reinterpret_cast<const half8*>(&Vth[df*16 + lr][c*32 + lg*8]);
        oacc[df] = __builtin_amdgcn_mfma_f32_16x16x32_f16(pah, vfh, oacc[df], 0, 0, 0);
        oacc[df] = __builtin_amdgcn_mfma_f32_16x16x32_f16(pal, vfh, oacc[df], 0, 0, 0);
#if V_LO
        half8 vfl = *reinterpret_cast<const half8*>(&Vtl[df*16 + lr][c*32 + lg*8]);
        oacc[df] = __builtin_amdgcn_mfma_f32_16x16x32_f16(pah, vfl, oacc[df], 0, 0, 0);
#endif
      }
    }
  }
  // epilogue: normalize + gate, emit fp16 hi/lo split of ypre
#pragma unroll
  for (int r = 0; r < 4; ++r) {
    const int t = qt*64 + wv*16 + lg*4 + r;
    const float g = gates[((size_t)(b*TT + t)) * HH + h];
    const float sc = g / rowL[r];
#pragma unroll
    for (int df = 0; df < 4; ++df) {
      const float v = oacc[df][r] * sc;
      const _Float16 vh = (_Float16)v;
      const size_t off = ((size_t)(b*TT + t)) * DD + h*DH + df*16 + lr;
      yhi[off] = vh;
      ylo[off] = (_Float16)(v - (float)vh);
    }
  }
}

extern "C" void kernel_launch(void* const* d_in, const int* in_sizes, int n_in,
                              void* d_out, int out_size, void* d_ws, size_t ws_size,
                              hipStream_t stream) {
  (void)in_sizes; (void)n_in; (void)out_size; (void)ws_size;
  const float* x    = (const float*)d_in[0];
  const float* Wqkv = (const float*)d_in[1];
  const float* Wr   = (const float*)d_in[2];
  const float* Wo   = (const float*)d_in[3];
  float* out = (float*)d_out;

  _Float16* qkvh = (_Float16*)d_ws;                 // [BTOT][3*DD] fp16 hi (25.2 MB)
  _Float16* qkvl = qkvh + (size_t)BTOT * 3 * DD;    // fp16 lo (25.2 MB)
  float*    gates = (float*)(qkvl + (size_t)BTOT * 3 * DD);
  _Float16* x_hi = (_Float16*)(gates + (size_t)BTOT * HH);
  _Float16* x_lo = x_hi + (size_t)BTOT * DD;
  _Float16* Wqh  = x_lo + (size_t)BTOT * DD;
  _Float16* Wql  = Wqh + (size_t)DD * 3 * DD;
  _Float16* Woh  = Wql + (size_t)DD * 3 * DD;
  _Float16* Wol  = Woh + (size_t)DD * DD;
  // ypre hi/lo alias x_hi/x_lo (x split is dead after the qkv GEMM)
  _Float16* yhi = x_hi;
  _Float16* ylo = x_lo;

  split_f32<<<1024, 256, 0, stream>>>(x, x_hi, x_lo, BTOT * DD / 4);
  wsplit_t<<<dim3(3*DD/64, DD/64), 256, 0, stream>>>(Wqkv, Wqh, Wql, DD, 3*DD);
  wsplit_t<<<dim3(DD/64, DD/64), 256, 0, stream>>>(Wo, Woh, Wol, DD, DD);
  router_kernel<<<BTOT, 64, 0, stream>>>(x, Wr, gates);
  hgemm_split<true><<<dim3(3*DD/128, BTOT/128), 256, 0, stream>>>(
      x_hi, x_lo, Wqh, Wql, nullptr, qkvh, qkvl, BTOT, 3*DD, DD);
  attn_mfma<<<(TT/64)*BB*HH, 256, 0, stream>>>(qkvh, qkvl, gates, yhi, ylo);
  hgemm_split<false><<<dim3(DD/128, BTOT/128), 256, 0, stream>>>(
      yhi, ylo, Woh, Wol, out, nullptr, nullptr, BTOT, DD, DD);
}